// Round 1
// baseline (554.682 us; speedup 1.0000x reference)
//
#include <hip/hip_runtime.h>
#include <hip/hip_bf16.h>

#define BB 2
#define TT 512
#define SS 400
#define HH 1024
#define VV 50257
#define MM (BB*TT)

#define BM 128
#define BN 128
#define BK 32
#define NTILE ((VV + BN - 1) / BN)   // 393

typedef __attribute__((ext_vector_type(8))) short short8;
typedef __attribute__((ext_vector_type(4))) float f32x4;

static __device__ __forceinline__ unsigned short f2bf(float f) {
    union { float f; unsigned u; } x;
    x.f = f;
    unsigned r = x.u + 0x7FFFu + ((x.u >> 16) & 1u);
    return (unsigned short)(r >> 16);
}

static __device__ __forceinline__ float get_invtemp(const int* tp) {
    int iv = *tp;
    float f;
    if (iv > 0 && iv < 100000) f = (float)iv;          // stored as int
    else                       f = __int_as_float(iv); // stored as float bits
    return 1.0f / f;
}

// ---- zero map + A accumulator ----
__global__ void zero2_k(int* a, int na, int* b, int nb) {
    int i = blockIdx.x * blockDim.x + threadIdx.x;
    int st = gridDim.x * blockDim.x;
    for (int t = i; t < na; t += st) a[t] = 0;
    for (int t = i; t < nb; t += st) b[t] = 0;
}

// ---- convert x (f32) -> bf16 ----
__global__ void cvt_x_k(const float* __restrict__ x, unsigned short* __restrict__ xb) {
    int i = blockIdx.x * 256 + threadIdx.x;   // 262144 float4 groups
    float4 v = ((const float4*)x)[i];
    ushort4 o;
    o.x = f2bf(v.x); o.y = f2bf(v.y); o.z = f2bf(v.z); o.w = f2bf(v.w);
    ((ushort4*)xb)[i] = o;
}

// ---- p_gen = sigmoid(x . pgen_w + pgen_b), one block per row ----
__global__ void pgen_k(const float* __restrict__ x, const float* __restrict__ pw,
                       const float* __restrict__ pb, float* __restrict__ pgen) {
    int m = blockIdx.x, tid = threadIdx.x;
    float s = 0.f;
    for (int h = tid; h < HH; h += 256) s += x[(size_t)m * HH + h] * pw[h];
    for (int off = 32; off; off >>= 1) s += __shfl_down(s, off);
    __shared__ float red[4];
    if ((tid & 63) == 0) red[tid >> 6] = s;
    __syncthreads();
    if (tid == 0) {
        float t = red[0] + red[1] + red[2] + red[3] + pb[0];
        pgen[m] = 1.0f / (1.0f + __expf(-t));
    }
}

// ---- build per-batch canonical-slot map: map[b][id] = s+1 (first writer wins) ----
__global__ void map_build_k(const int* __restrict__ enc, int* __restrict__ mapv) {
    int t = blockIdx.x * blockDim.x + threadIdx.x;
    if (t >= BB * SS) return;
    int b = t / SS, s = t % SS;
    int id = enc[b * SS + s];
    atomicCAS(&mapv[(size_t)b * VV + id], 0, s + 1);
}

// ---- attn softmax + (1-pgen) scale + accumulate into per-row slot matrix ----
__global__ void attn_k(const float* __restrict__ attn, const int* __restrict__ enc,
                       const int* __restrict__ mapv, const float* __restrict__ pgen,
                       float* __restrict__ Aacc, const int* __restrict__ tempp) {
    int m = blockIdx.x, tid = threadIdx.x;
    int b = m >> 9;   // T = 512
    float invt = get_invtemp(tempp);
    __shared__ float sv[SS];
    __shared__ float red[256];
    float loc = -1e30f;
    for (int s = tid; s < SS; s += 256) {
        float v = attn[(size_t)m * SS + s] * invt;
        sv[s] = v;
        loc = fmaxf(loc, v);
    }
    red[tid] = loc; __syncthreads();
    for (int h = 128; h; h >>= 1) { if (tid < h) red[tid] = fmaxf(red[tid], red[tid + h]); __syncthreads(); }
    float mx = red[0]; __syncthreads();
    float ls = 0.f;
    for (int s = tid; s < SS; s += 256) ls += __expf(sv[s] - mx);
    red[tid] = ls; __syncthreads();
    for (int h = 128; h; h >>= 1) { if (tid < h) red[tid] += red[tid + h]; __syncthreads(); }
    float scale = (1.0f - pgen[m]) / red[0];
    for (int s = tid; s < SS; s += 256) {
        int id = enc[b * SS + s];
        int s0 = mapv[(size_t)b * VV + id] - 1;
        atomicAdd(&Aacc[(size_t)m * SS + s0], __expf(sv[s] - mx) * scale);
    }
}

// ---- GEMM: logits[m][v] = sum_h xb[m][h] * W[v][h] + bias[v]  (bf16 MFMA) ----
__global__ __launch_bounds__(256) void gemm_logits_k(
    const unsigned short* __restrict__ xb, const float* __restrict__ W,
    const float* __restrict__ bias, float* __restrict__ out) {
    __shared__ unsigned short As[BM][40];   // padded: 40*2=80B stride -> conflict-free-ish
    __shared__ unsigned short Bs[BN][40];
    int bid = blockIdx.x;
    int mt = bid & 7;       // m-tile fast -> 8 consecutive blocks share W panel (L2)
    int nt = bid >> 3;
    int m0 = mt * BM, n0 = nt * BN;
    int tid = threadIdx.x;
    int lid = tid & 63, w = tid >> 6;
    int wr = w >> 1, wc = w & 1;
    int row16 = lid & 15, kg = lid >> 4;

    f32x4 acc[4][4];
#pragma unroll
    for (int i = 0; i < 4; i++)
#pragma unroll
        for (int j = 0; j < 4; j++) acc[i][j] = (f32x4){0.f, 0.f, 0.f, 0.f};

    int tr = tid >> 3;            // 0..31
    int tc = (tid & 7) << 2;      // 0,4,...,28

    for (int kt = 0; kt < HH / BK; ++kt) {
        int k0 = kt * BK;
        __syncthreads();
#pragma unroll
        for (int i = 0; i < 4; i++) {
            int r = tr + 32 * i;
            ushort4 a4 = *(const ushort4*)&xb[(size_t)(m0 + r) * HH + k0 + tc];
            *(ushort4*)&As[r][tc] = a4;
            int v = n0 + r; v = (v < VV) ? v : (VV - 1);   // clamp tail reads
            float4 w4 = *(const float4*)&W[(size_t)v * HH + k0 + tc];
            ushort4 b4;
            b4.x = f2bf(w4.x); b4.y = f2bf(w4.y); b4.z = f2bf(w4.z); b4.w = f2bf(w4.w);
            *(ushort4*)&Bs[r][tc] = b4;
        }
        __syncthreads();
        short8 af[4], bf[4];
#pragma unroll
        for (int i = 0; i < 4; i++) {
            af[i] = *(const short8*)&As[wr * 64 + i * 16 + row16][kg * 8];
            bf[i] = *(const short8*)&Bs[wc * 64 + i * 16 + row16][kg * 8];
        }
#pragma unroll
        for (int mi = 0; mi < 4; mi++)
#pragma unroll
            for (int ni = 0; ni < 4; ni++)
                acc[mi][ni] = __builtin_amdgcn_mfma_f32_16x16x32_bf16(af[mi], bf[ni], acc[mi][ni], 0, 0, 0);
    }
    // epilogue: D layout col=lane&15, row=(lane>>4)*4+j
#pragma unroll
    for (int ni = 0; ni < 4; ni++) {
        int gn = n0 + wc * 64 + ni * 16 + row16;
        if (gn < VV) {
            float bv = bias[gn];
#pragma unroll
            for (int mi = 0; mi < 4; mi++) {
                int gmb = m0 + wr * 64 + mi * 16 + (kg << 2);
#pragma unroll
                for (int j = 0; j < 4; j++)
                    out[(size_t)(gmb + j) * VV + gn] = acc[mi][ni][j] + bv;
            }
        }
    }
}

// ---- per-row online max/sum over V -> lse[m] ----
__global__ void rowreduce_k(const float* __restrict__ out, float* __restrict__ lse,
                            const int* __restrict__ tempp) {
    int m = blockIdx.x, tid = threadIdx.x;
    float invt = get_invtemp(tempp);
    const float* row = out + (size_t)m * VV;
    float mi = -1e30f, si = 0.f;
    for (int v = tid; v < VV; v += 256) {
        float x = row[v] * invt;
        float nm = fmaxf(mi, x);
        si = si * __expf(mi - nm) + __expf(x - nm);
        mi = nm;
    }
    __shared__ float sm[256], ss[256];
    sm[tid] = mi; ss[tid] = si; __syncthreads();
    for (int h = 128; h; h >>= 1) {
        if (tid < h) {
            float m2 = sm[tid + h], s2 = ss[tid + h];
            float nm = fmaxf(sm[tid], m2);
            ss[tid] = ss[tid] * __expf(sm[tid] - nm) + s2 * __expf(m2 - nm);
            sm[tid] = nm;
        }
        __syncthreads();
    }
    if (tid == 0) lse[m] = sm[0] + __logf(ss[0]);
}

// ---- finalize: out = log(pgen*softmax + scatter + 1e-40) in place ----
__global__ void finalize_k(float* __restrict__ out, const float* __restrict__ pgen,
                           const float* __restrict__ lse, const int* __restrict__ mapv,
                           const float* __restrict__ Aacc, const int* __restrict__ tempp) {
    int m = blockIdx.y;
    int v = blockIdx.x * 256 + threadIdx.x;
    if (v >= VV) return;
    int b = m >> 9;
    float invt = get_invtemp(tempp);
    size_t idx = (size_t)m * VV + v;
    float l = out[idx];
    float p = pgen[m] * __expf(l * invt - lse[m]);
    int j = mapv[(size_t)b * VV + v];
    if (j) p += Aacc[(size_t)m * SS + (j - 1)];
    out[idx] = __logf(p + 1e-40f);
}

extern "C" void kernel_launch(void* const* d_in, const int* in_sizes, int n_in,
                              void* d_out, int out_size, void* d_ws, size_t ws_size,
                              hipStream_t stream) {
    const float* x      = (const float*)d_in[0];
    const float* attn   = (const float*)d_in[1];
    const int*   enc    = (const int*)d_in[2];
    const int*   temp   = (const int*)d_in[3];
    const float* proj_w = (const float*)d_in[4];
    const float* proj_b = (const float*)d_in[5];
    const float* pgen_w = (const float*)d_in[6];
    const float* pgen_b = (const float*)d_in[7];
    float* out = (float*)d_out;

    char* ws = (char*)d_ws;
    unsigned short* xb   = (unsigned short*)(ws + 0);        // 2 MB
    float*          pgen = (float*)(ws + 2097152);           // 4 KB
    float*          lse  = (float*)(ws + 2101248);           // 4 KB
    int*            mapv = (int*)(ws + 2105344);             // 402 KB
    float*          Aacc = (float*)(ws + 2507776);           // 1.6 MB

    zero2_k<<<512, 256, 0, stream>>>(mapv, BB * VV, (int*)Aacc, MM * SS);
    cvt_x_k<<<1024, 256, 0, stream>>>(x, xb);
    pgen_k<<<MM, 256, 0, stream>>>(x, pgen_w, pgen_b, pgen);
    map_build_k<<<4, 256, 0, stream>>>(enc, mapv);
    attn_k<<<MM, 256, 0, stream>>>(attn, enc, mapv, pgen, Aacc, temp);
    gemm_logits_k<<<8 * NTILE, 256, 0, stream>>>(xb, proj_w, proj_b, out);
    rowreduce_k<<<MM, 256, 0, stream>>>(out, lse, temp);
    finalize_k<<<dim3((VV + 255) / 256, MM), 256, 0, stream>>>(out, pgen, lse, mapv, Aacc, temp);
}

// Round 2
// 447.328 us; speedup vs baseline: 1.2400x; 1.2400x over previous
//
#include <hip/hip_runtime.h>
#include <hip/hip_bf16.h>

#define BB 2
#define TT 512
#define SS 400
#define HH 1024
#define VV 50257
#define MM (BB*TT)

#define NTILE 393          // ceil(VV/128)
#define NT_PAD 400         // padded to 50 panels per XCD
#define VPAD 50304         // 393*128, bf16-W row padding

typedef __attribute__((ext_vector_type(8))) short short8;
typedef __attribute__((ext_vector_type(4))) float f32x4;

#define AS1 __attribute__((address_space(1)))
#define AS3 __attribute__((address_space(3)))

static __device__ __forceinline__ void gl_lds16(const unsigned short* g, unsigned short* l) {
    __builtin_amdgcn_global_load_lds((const AS1 unsigned int*)(g), (AS3 unsigned int*)(l), 16, 0, 0);
}

static __device__ __forceinline__ unsigned short f2bf(float f) {
    union { float f; unsigned u; } x;
    x.f = f;
    unsigned r = x.u + 0x7FFFu + ((x.u >> 16) & 1u);
    return (unsigned short)(r >> 16);
}

static __device__ __forceinline__ float get_invtemp(const int* tp) {
    int iv = *tp;
    float f;
    if (iv > 0 && iv < 100000) f = (float)iv;
    else                       f = __int_as_float(iv);
    return 1.0f / f;
}

// ---- zero map + A accumulator ----
__global__ void zero2_k(int* a, int na, int* b, int nb) {
    int i = blockIdx.x * blockDim.x + threadIdx.x;
    int st = gridDim.x * blockDim.x;
    for (int t = i; t < na; t += st) a[t] = 0;
    for (int t = i; t < nb; t += st) b[t] = 0;
}

// ---- convert x (f32) -> bf16 ----
__global__ void cvt_x_k(const float* __restrict__ x, unsigned short* __restrict__ xb) {
    int i = blockIdx.x * 256 + threadIdx.x;
    float4 v = ((const float4*)x)[i];
    ushort4 o;
    o.x = f2bf(v.x); o.y = f2bf(v.y); o.z = f2bf(v.z); o.w = f2bf(v.w);
    ((ushort4*)xb)[i] = o;
}

// ---- convert W (f32, VV rows) -> Wb (bf16, VPAD rows, zero-padded) ----
__global__ void cvt_w_k(const float* __restrict__ W, unsigned short* __restrict__ Wb) {
    size_t g = (size_t)blockIdx.x * 256 + threadIdx.x;   // one per 8 elems
    size_t e0 = g * 8;
    int v = (int)(e0 >> 10);
    short8 o;
    if (v < VV) {
        float4 a = *(const float4*)(W + e0);
        float4 b = *(const float4*)(W + e0 + 4);
        o[0] = f2bf(a.x); o[1] = f2bf(a.y); o[2] = f2bf(a.z); o[3] = f2bf(a.w);
        o[4] = f2bf(b.x); o[5] = f2bf(b.y); o[6] = f2bf(b.z); o[7] = f2bf(b.w);
    } else {
        o = (short8){0,0,0,0,0,0,0,0};
    }
    *(short8*)(Wb + e0) = o;
}

// ---- p_gen ----
__global__ void pgen_k(const float* __restrict__ x, const float* __restrict__ pw,
                       const float* __restrict__ pb, float* __restrict__ pgen) {
    int m = blockIdx.x, tid = threadIdx.x;
    float s = 0.f;
    for (int h = tid; h < HH; h += 256) s += x[(size_t)m * HH + h] * pw[h];
    for (int off = 32; off; off >>= 1) s += __shfl_down(s, off);
    __shared__ float red[4];
    if ((tid & 63) == 0) red[tid >> 6] = s;
    __syncthreads();
    if (tid == 0) {
        float t = red[0] + red[1] + red[2] + red[3] + pb[0];
        pgen[m] = 1.0f / (1.0f + __expf(-t));
    }
}

// ---- canonical slot map ----
__global__ void map_build_k(const int* __restrict__ enc, int* __restrict__ mapv) {
    int t = blockIdx.x * blockDim.x + threadIdx.x;
    if (t >= BB * SS) return;
    int b = t / SS, s = t % SS;
    int id = enc[b * SS + s];
    atomicCAS(&mapv[(size_t)b * VV + id], 0, s + 1);
}

// ---- attn softmax + (1-pgen) -> slot matrix ----
__global__ void attn_k(const float* __restrict__ attn, const int* __restrict__ enc,
                       const int* __restrict__ mapv, const float* __restrict__ pgen,
                       float* __restrict__ Aacc, const int* __restrict__ tempp) {
    int m = blockIdx.x, tid = threadIdx.x;
    int b = m >> 9;
    float invt = get_invtemp(tempp);
    __shared__ float sv[SS];
    __shared__ float red[256];
    float loc = -1e30f;
    for (int s = tid; s < SS; s += 256) {
        float v = attn[(size_t)m * SS + s] * invt;
        sv[s] = v;
        loc = fmaxf(loc, v);
    }
    red[tid] = loc; __syncthreads();
    for (int h = 128; h; h >>= 1) { if (tid < h) red[tid] = fmaxf(red[tid], red[tid + h]); __syncthreads(); }
    float mx = red[0]; __syncthreads();
    float ls = 0.f;
    for (int s = tid; s < SS; s += 256) ls += __expf(sv[s] - mx);
    red[tid] = ls; __syncthreads();
    for (int h = 128; h; h >>= 1) { if (tid < h) red[tid] += red[tid + h]; __syncthreads(); }
    float scale = (1.0f - pgen[m]) / red[0];
    for (int s = tid; s < SS; s += 256) {
        int id = enc[b * SS + s];
        int s0 = mapv[(size_t)b * VV + id] - 1;
        atomicAdd(&Aacc[(size_t)m * SS + s0], __expf(sv[s] - mx) * scale);
    }
}

// ---- GEMM v2: global_load_lds staging, bf16 W, XCD-local panels ----
// grid = 8 * NT_PAD blocks of 256 threads
__global__ __launch_bounds__(256) void gemm2_k(
    const unsigned short* __restrict__ xb, const unsigned short* __restrict__ Wb,
    const float* __restrict__ bias, float* __restrict__ out) {
    __shared__ unsigned short As[128 * 64];   // 16 KB
    __shared__ unsigned short Bs[128 * 64];   // 16 KB

    int wgid = blockIdx.x;
    int xcd = wgid & 7;
    int l = wgid >> 3;               // 0..399
    int nt = xcd * 50 + (l >> 3);    // 50 panels per XCD
    int mt = l & 7;
    if (nt >= NTILE) return;
    int m0 = mt * 128, n0 = nt * 128;

    int tid = threadIdx.x;
    int lane = tid & 63, w = tid >> 6;
    int wr = w >> 1, wc = w & 1;
    int r15 = lane & 15, kg = lane >> 4;

    // staging source offsets (global pre-swizzled so linear LDS holds XOR layout)
    size_t aoff[4], boff[4];
#pragma unroll
    for (int i = 0; i < 4; i++) {
        int q = i * 256 + tid;           // chunk id 0..1023
        int row = q >> 3;
        int jc = (q & 7) ^ (row & 7);
        aoff[i] = (size_t)(m0 + row) * HH + jc * 8;
        boff[i] = (size_t)(n0 + row) * HH + jc * 8;
    }

    f32x4 acc[4][4];
#pragma unroll
    for (int i = 0; i < 4; i++)
#pragma unroll
        for (int j = 0; j < 4; j++) acc[i][j] = (f32x4){0.f, 0.f, 0.f, 0.f};

    for (int kt = 0; kt < HH / 64; ++kt) {
        int k0 = kt * 64;
#pragma unroll
        for (int i = 0; i < 4; i++) {
            gl_lds16(xb + aoff[i] + k0, As + (i * 256 + w * 64) * 8);
            gl_lds16(Wb + boff[i] + k0, Bs + (i * 256 + w * 64) * 8);
        }
        __syncthreads();   // drains vmcnt before any wave reads LDS
#pragma unroll
        for (int h = 0; h < 2; h++) {
            short8 af[4], bf[4];
#pragma unroll
            for (int mi = 0; mi < 4; mi++) {
                int row = wr * 64 + mi * 16 + r15;
                int jc = ((h << 2) | kg) ^ (row & 7);
                af[mi] = *(const short8*)&As[row * 64 + jc * 8];
            }
#pragma unroll
            for (int ni = 0; ni < 4; ni++) {
                int row = wc * 64 + ni * 16 + r15;
                int jc = ((h << 2) | kg) ^ (row & 7);
                bf[ni] = *(const short8*)&Bs[row * 64 + jc * 8];
            }
#pragma unroll
            for (int mi = 0; mi < 4; mi++)
#pragma unroll
                for (int ni = 0; ni < 4; ni++)
                    acc[mi][ni] = __builtin_amdgcn_mfma_f32_16x16x32_bf16(af[mi], bf[ni], acc[mi][ni], 0, 0, 0);
        }
        __syncthreads();   // before overwriting tile
    }

#pragma unroll
    for (int ni = 0; ni < 4; ni++) {
        int gn = n0 + wc * 64 + ni * 16 + r15;
        if (gn < VV) {
            float bv = bias[gn];
#pragma unroll
            for (int mi = 0; mi < 4; mi++) {
                int gmb = m0 + wr * 64 + mi * 16 + (kg << 2);
#pragma unroll
                for (int j = 0; j < 4; j++)
                    out[(size_t)(gmb + j) * VV + gn] = acc[mi][ni][j] + bv;
            }
        }
    }
}

// ---- fallback GEMM (reads f32 W directly; round-1 version) ----
__global__ __launch_bounds__(256) void gemm_old_k(
    const unsigned short* __restrict__ xb, const float* __restrict__ W,
    const float* __restrict__ bias, float* __restrict__ out) {
    __shared__ unsigned short As[128][40];
    __shared__ unsigned short Bs[128][40];
    int bid = blockIdx.x;
    int mt = bid & 7;
    int nt = bid >> 3;
    int m0 = mt * 128, n0 = nt * 128;
    int tid = threadIdx.x;
    int lid = tid & 63, w = tid >> 6;
    int wr = w >> 1, wc = w & 1;
    int row16 = lid & 15, kg = lid >> 4;

    f32x4 acc[4][4];
#pragma unroll
    for (int i = 0; i < 4; i++)
#pragma unroll
        for (int j = 0; j < 4; j++) acc[i][j] = (f32x4){0.f, 0.f, 0.f, 0.f};

    int tr = tid >> 3;
    int tc = (tid & 7) << 2;

    for (int kt = 0; kt < HH / 32; ++kt) {
        int k0 = kt * 32;
        __syncthreads();
#pragma unroll
        for (int i = 0; i < 4; i++) {
            int r = tr + 32 * i;
            ushort4 a4 = *(const ushort4*)&xb[(size_t)(m0 + r) * HH + k0 + tc];
            *(ushort4*)&As[r][tc] = a4;
            int v = n0 + r; v = (v < VV) ? v : (VV - 1);
            float4 w4 = *(const float4*)&W[(size_t)v * HH + k0 + tc];
            ushort4 b4;
            b4.x = f2bf(w4.x); b4.y = f2bf(w4.y); b4.z = f2bf(w4.z); b4.w = f2bf(w4.w);
            *(ushort4*)&Bs[r][tc] = b4;
        }
        __syncthreads();
        short8 af[4], bf[4];
#pragma unroll
        for (int i = 0; i < 4; i++) {
            af[i] = *(const short8*)&As[wr * 64 + i * 16 + row16][kg * 8];
            bf[i] = *(const short8*)&Bs[wc * 64 + i * 16 + row16][kg * 8];
        }
#pragma unroll
        for (int mi = 0; mi < 4; mi++)
#pragma unroll
            for (int ni = 0; ni < 4; ni++)
                acc[mi][ni] = __builtin_amdgcn_mfma_f32_16x16x32_bf16(af[mi], bf[ni], acc[mi][ni], 0, 0, 0);
    }
#pragma unroll
    for (int ni = 0; ni < 4; ni++) {
        int gn = n0 + wc * 64 + ni * 16 + row16;
        if (gn < VV) {
            float bv = bias[gn];
#pragma unroll
            for (int mi = 0; mi < 4; mi++) {
                int gmb = m0 + wr * 64 + mi * 16 + (kg << 2);
#pragma unroll
                for (int j = 0; j < 4; j++)
                    out[(size_t)(gmb + j) * VV + gn] = acc[mi][ni][j] + bv;
            }
        }
    }
}

// ---- per-row lse over V (float4, per-row alignment skip) ----
__global__ void rowreduce_k(const float* __restrict__ out, float* __restrict__ lse,
                            const int* __restrict__ tempp) {
    int m = blockIdx.x, tid = threadIdx.x;
    float invt = get_invtemp(tempp);
    const float* row = out + (size_t)m * VV;
    int sk = (-m) & 3;                 // (m*VV)%4 == m%4
    int nchunk = (VV - sk) >> 2;
    float mi = -1e30f, si = 0.f;
    for (int c = tid; c < nchunk; c += 256) {
        float4 x4 = *(const float4*)(row + sk + 4 * c);
        float xs[4] = {x4.x, x4.y, x4.z, x4.w};
#pragma unroll
        for (int j = 0; j < 4; j++) {
            float x = xs[j] * invt;
            float nm = fmaxf(mi, x);
            si = si * __expf(mi - nm) + __expf(x - nm);
            mi = nm;
        }
    }
    if (tid == 0) {
        for (int v = 0; v < sk; v++) {
            float x = row[v] * invt;
            float nm = fmaxf(mi, x);
            si = si * __expf(mi - nm) + __expf(x - nm);
            mi = nm;
        }
        for (int v = sk + 4 * nchunk; v < VV; v++) {
            float x = row[v] * invt;
            float nm = fmaxf(mi, x);
            si = si * __expf(mi - nm) + __expf(x - nm);
            mi = nm;
        }
    }
    __shared__ float sm[256], ss[256];
    sm[tid] = mi; ss[tid] = si; __syncthreads();
    for (int h = 128; h; h >>= 1) {
        if (tid < h) {
            float m2 = sm[tid + h], s2 = ss[tid + h];
            float nm = fmaxf(sm[tid], m2);
            ss[tid] = ss[tid] * __expf(sm[tid] - nm) + s2 * __expf(m2 - nm);
            sm[tid] = nm;
        }
        __syncthreads();
    }
    if (tid == 0) lse[m] = sm[0] + __logf(ss[0]);
}

// ---- finalize (float4 in/out, scalar map gather) ----
__global__ void finalize_k(float* __restrict__ out, const float* __restrict__ pgen,
                           const float* __restrict__ lse, const int* __restrict__ mapv,
                           const float* __restrict__ Aacc, const int* __restrict__ tempp) {
    int m = blockIdx.y;
    int b = m >> 9;
    float invt = get_invtemp(tempp);
    float pg = pgen[m], L = lse[m];
    size_t base = (size_t)m * VV;
    const int* mrow = mapv + (size_t)b * VV;
    const float* arow = Aacc + (size_t)m * SS;
    int sk = (-m) & 3;
    int nchunk = (VV - sk) >> 2;
    int c = blockIdx.x * 256 + threadIdx.x;
    if (c < nchunk) {
        int v0 = sk + 4 * c;
        float4 l4 = *(const float4*)(out + base + v0);
        float xs[4] = {l4.x, l4.y, l4.z, l4.w};
        float rs[4];
#pragma unroll
        for (int j = 0; j < 4; j++) {
            float p = pg * __expf(xs[j] * invt - L);
            int jm = mrow[v0 + j];
            if (jm) p += arow[jm - 1];
            rs[j] = __logf(p + 1e-40f);
        }
        float4 o4 = {rs[0], rs[1], rs[2], rs[3]};
        *(float4*)(out + base + v0) = o4;
    }
    if (blockIdx.x == 0 && threadIdx.x == 0) {
        for (int v = 0; v < sk; v++) {
            float p = pg * __expf(out[base + v] * invt - L);
            int jm = mrow[v];
            if (jm) p += arow[jm - 1];
            out[base + v] = __logf(p + 1e-40f);
        }
        for (int v = sk + 4 * nchunk; v < VV; v++) {
            float p = pg * __expf(out[base + v] * invt - L);
            int jm = mrow[v];
            if (jm) p += arow[jm - 1];
            out[base + v] = __logf(p + 1e-40f);
        }
    }
}

extern "C" void kernel_launch(void* const* d_in, const int* in_sizes, int n_in,
                              void* d_out, int out_size, void* d_ws, size_t ws_size,
                              hipStream_t stream) {
    const float* x      = (const float*)d_in[0];
    const float* attn   = (const float*)d_in[1];
    const int*   enc    = (const int*)d_in[2];
    const int*   temp   = (const int*)d_in[3];
    const float* proj_w = (const float*)d_in[4];
    const float* proj_b = (const float*)d_in[5];
    const float* pgen_w = (const float*)d_in[6];
    const float* pgen_b = (const float*)d_in[7];
    float* out = (float*)d_out;

    char* ws = (char*)d_ws;
    const size_t WB_BYTES = (size_t)VPAD * HH * 2;       // 103,022,592

    // big-ws path layout
    size_t o_wb   = 0;
    size_t o_xb   = o_wb + WB_BYTES;
    size_t o_pgen = o_xb + 2097152;
    size_t o_lse  = o_pgen + 4096;
    size_t o_map  = o_lse + 4096;
    size_t o_aacc = o_map + 402432;
    size_t need   = o_aacc + (size_t)MM * SS * 4;        // ~107.2 MB

    if (ws_size >= need) {
        unsigned short* wb   = (unsigned short*)(ws + o_wb);
        unsigned short* xb   = (unsigned short*)(ws + o_xb);
        float*          pgen = (float*)(ws + o_pgen);
        float*          lse  = (float*)(ws + o_lse);
        int*            mapv = (int*)(ws + o_map);
        float*          Aacc = (float*)(ws + o_aacc);

        zero2_k<<<512, 256, 0, stream>>>(mapv, BB * VV, (int*)Aacc, MM * SS);
        cvt_x_k<<<1024, 256, 0, stream>>>(x, xb);
        cvt_w_k<<<(VPAD * HH / 8 + 255) / 256, 256, 0, stream>>>(proj_w, wb);
        pgen_k<<<MM, 256, 0, stream>>>(x, pgen_w, pgen_b, pgen);
        map_build_k<<<4, 256, 0, stream>>>(enc, mapv);
        attn_k<<<MM, 256, 0, stream>>>(attn, enc, mapv, pgen, Aacc, temp);
        gemm2_k<<<8 * NT_PAD, 256, 0, stream>>>(xb, wb, proj_b, out);
        rowreduce_k<<<MM, 256, 0, stream>>>(out, lse, temp);
        finalize_k<<<dim3(50, MM), 256, 0, stream>>>(out, pgen, lse, mapv, Aacc, temp);
    } else {
        // fallback: round-1 layout
        unsigned short* xb   = (unsigned short*)(ws + 0);
        float*          pgen = (float*)(ws + 2097152);
        float*          lse  = (float*)(ws + 2101248);
        int*            mapv = (int*)(ws + 2105344);
        float*          Aacc = (float*)(ws + 2507776);

        zero2_k<<<512, 256, 0, stream>>>(mapv, BB * VV, (int*)Aacc, MM * SS);
        cvt_x_k<<<1024, 256, 0, stream>>>(x, xb);
        pgen_k<<<MM, 256, 0, stream>>>(x, pgen_w, pgen_b, pgen);
        map_build_k<<<4, 256, 0, stream>>>(enc, mapv);
        attn_k<<<MM, 256, 0, stream>>>(attn, enc, mapv, pgen, Aacc, temp);
        gemm_old_k<<<8 * NTILE, 256, 0, stream>>>(xb, proj_w, proj_b, out);
        rowreduce_k<<<MM, 256, 0, stream>>>(out, lse, temp);
        finalize_k<<<dim3(50, MM), 256, 0, stream>>>(out, pgen, lse, mapv, Aacc, temp);
    }
}